// Round 13
// baseline (334.340 us; speedup 1.0000x reference)
//
#include <hip/hip_runtime.h>
#include <hip/hip_bf16.h>
#include <hip/hip_fp16.h>
#include <math.h>

#define L2E 1.44269504f
#define LN2 0.69314718f
#define TSH 136   // halves per table row (272 B, 16B-aligned)

__device__ __forceinline__ float sigf(float x){ return 1.0f/(1.0f+expf(-x)); }

__device__ __forceinline__ float quad_max(float x) {
    x = fmaxf(x, __int_as_float(__builtin_amdgcn_mov_dpp(__float_as_int(x), 0xB1, 0xF, 0xF, true)));
    x = fmaxf(x, __int_as_float(__builtin_amdgcn_mov_dpp(__float_as_int(x), 0x4E, 0xF, 0xF, true)));
    return x;
}
__device__ __forceinline__ float quad_sum(float x) {
    x += __int_as_float(__builtin_amdgcn_mov_dpp(__float_as_int(x), 0xB1, 0xF, 0xF, true));
    x += __int_as_float(__builtin_amdgcn_mov_dpp(__float_as_int(x), 0x4E, 0xF, 0xF, true));
    return x;
}
__device__ __forceinline__ void cvt8(uint4 q, float* f) {
    float2 p;
    p = __half22float2(*(const __half2*)&q.x); f[0]=p.x; f[1]=p.y;
    p = __half22float2(*(const __half2*)&q.y); f[2]=p.x; f[3]=p.y;
    p = __half22float2(*(const __half2*)&q.z); f[4]=p.x; f[5]=p.y;
    p = __half22float2(*(const __half2*)&q.w); f[6]=p.x; f[7]=p.y;
}

// ---------------------------------------------------------------- prep + embed + out-zero (R10 bf16 version)
__global__ __launch_bounds__(256) void prep_all(const float* __restrict__ Whh_f, const float* __restrict__ Whh_b,
                             const float* __restrict__ bih_f, const float* __restrict__ bhh_f,
                             const float* __restrict__ bih_b, const float* __restrict__ bhh_b,
                             __hip_bfloat162* __restrict__ wTf, __hip_bfloat162* __restrict__ wTb,
                             float* __restrict__ biasf, float* __restrict__ biasb,
                             const int* __restrict__ sents, const float* __restrict__ mask,
                             const float* __restrict__ emb, float* __restrict__ embeds,
                             float* __restrict__ out) {
    if (blockIdx.x < 1024) {
        int idx = blockIdx.x * 256 + threadIdx.x;      // 0 .. 262143
        int dir = idx >> 17;
        int r   = idx & 131071;
        int k2  = r >> 10;
        int rem = r & 1023;
        int j   = rem >> 2;      // cell
        int qg  = rem & 3;       // gate (i,f,g,o)
        const float* W = dir ? Whh_b : Whh_f;
        int row = qg * 256 + j;
        __hip_bfloat162 t;
        t.x = __float2bfloat16(W[row*256 + 2*k2]);
        t.y = __float2bfloat16(W[row*256 + 2*k2 + 1]);
        (dir ? wTb : wTf)[r] = t;
        if (idx < 1024)       biasf[idx]      = bih_f[idx]      + bhh_f[idx];
        else if (idx < 2048)  biasb[idx-1024] = bih_b[idx-1024] + bhh_b[idx-1024];
        if (idx == 0) out[0] = 0.0f;
    } else {
        int bl = blockIdx.x - 1024;   // 0..511
        int d  = threadIdx.x;         // 0..255
        const int*   srow = sents + bl*32;
        const float* mrow = mask  + bl*32;
        float acc = 0.0f, el = 0.0f;
        for (int w = 0; w < 32; ++w) {
            float m = mrow[w];
            el  += m;
            acc += emb[(size_t)srow[w]*256 + d] * m;
        }
        float den = el + (el == 0.0f ? 1.0f : 0.0f);
        embeds[bl*256 + d] = acc / den;
    }
}

// ---------------------------------------------------------------- 64x64 GEMM body, 4x4 micro-tile
__device__ __forceinline__ void gemm64_body(const float* __restrict__ A,
                                            const float* __restrict__ Bm,
                                            const float* __restrict__ bias,
                                            float* __restrict__ C,
                                            int N, int K, int bx, int by) {
    __shared__ __align__(16) float As[32][68];
    __shared__ __align__(16) float Bs[32][68];
    int tid = threadIdx.x;
    int tx = tid & 15, ty = tid >> 4;
    int row0 = bx * 64, col0 = by * 64;
    float acc[4][4];
    #pragma unroll
    for (int r = 0; r < 4; ++r)
        #pragma unroll
        for (int c = 0; c < 4; ++c) acc[r][c] = 0.0f;
    int lr = tid >> 2;
    int lc = (tid & 3) * 8;
    for (int k0 = 0; k0 < K; k0 += 32) {
        float4 a0 = *(const float4*)(A  + (size_t)(row0+lr)*K + k0 + lc);
        float4 a1 = *(const float4*)(A  + (size_t)(row0+lr)*K + k0 + lc + 4);
        float4 b0 = *(const float4*)(Bm + (size_t)(col0+lr)*K + k0 + lc);
        float4 b1 = *(const float4*)(Bm + (size_t)(col0+lr)*K + k0 + lc + 4);
        As[lc  ][lr] = a0.x; As[lc+1][lr] = a0.y; As[lc+2][lr] = a0.z; As[lc+3][lr] = a0.w;
        As[lc+4][lr] = a1.x; As[lc+5][lr] = a1.y; As[lc+6][lr] = a1.z; As[lc+7][lr] = a1.w;
        Bs[lc  ][lr] = b0.x; Bs[lc+1][lr] = b0.y; Bs[lc+2][lr] = b0.z; Bs[lc+3][lr] = b0.w;
        Bs[lc+4][lr] = b1.x; Bs[lc+5][lr] = b1.y; Bs[lc+6][lr] = b1.z; Bs[lc+7][lr] = b1.w;
        __syncthreads();
        #pragma unroll
        for (int kc = 0; kc < 32; ++kc) {
            float4 xa = *(const float4*)&As[kc][ty*4];
            float4 xb = *(const float4*)&Bs[kc][tx*4];
            acc[0][0] = fmaf(xa.x, xb.x, acc[0][0]);
            acc[0][1] = fmaf(xa.x, xb.y, acc[0][1]);
            acc[0][2] = fmaf(xa.x, xb.z, acc[0][2]);
            acc[0][3] = fmaf(xa.x, xb.w, acc[0][3]);
            acc[1][0] = fmaf(xa.y, xb.x, acc[1][0]);
            acc[1][1] = fmaf(xa.y, xb.y, acc[1][1]);
            acc[1][2] = fmaf(xa.y, xb.z, acc[1][2]);
            acc[1][3] = fmaf(xa.y, xb.w, acc[1][3]);
            acc[2][0] = fmaf(xa.z, xb.x, acc[2][0]);
            acc[2][1] = fmaf(xa.z, xb.y, acc[2][1]);
            acc[2][2] = fmaf(xa.z, xb.z, acc[2][2]);
            acc[2][3] = fmaf(xa.z, xb.w, acc[2][3]);
            acc[3][0] = fmaf(xa.w, xb.x, acc[3][0]);
            acc[3][1] = fmaf(xa.w, xb.y, acc[3][1]);
            acc[3][2] = fmaf(xa.w, xb.z, acc[3][2]);
            acc[3][3] = fmaf(xa.w, xb.w, acc[3][3]);
        }
        __syncthreads();
    }
    float4 bv = bias ? *(const float4*)&bias[col0 + tx*4] : make_float4(0.f,0.f,0.f,0.f);
    #pragma unroll
    for (int r = 0; r < 4; ++r) {
        float4 o;
        o.x = acc[r][0] + bv.x; o.y = acc[r][1] + bv.y;
        o.z = acc[r][2] + bv.z; o.w = acc[r][3] + bv.w;
        *(float4*)(C + (size_t)(row0 + ty*4 + r)*N + col0 + tx*4) = o;
    }
}

__global__ __launch_bounds__(256) void gemm_ih(const float* __restrict__ embeds,
                                               const float* __restrict__ Wf, const float* __restrict__ Wb,
                                               const float* __restrict__ biasf, const float* __restrict__ biasb,
                                               float* __restrict__ gxf, float* __restrict__ gxb) {
    int dir = blockIdx.z;
    gemm64_body(embeds, dir ? Wb : Wf, dir ? biasb : biasf, dir ? gxb : gxf,
                1024, 256, blockIdx.x, blockIdx.y);
}

__global__ __launch_bounds__(256) void gemm64(const float* __restrict__ A,
                                              const float* __restrict__ Bm,
                                              const float* __restrict__ bias,
                                              float* __restrict__ C,
                                              int N, int K, int sA, int sB, int sC) {
    gemm64_body(A + (size_t)blockIdx.z * sA, Bm + (size_t)blockIdx.z * sB, bias,
                C + (size_t)blockIdx.z * sC, N, K, blockIdx.x, blockIdx.y);
}

// ---------------------------------------------------------------- LSTM recurrence (R10 bf16 version)
__global__ __launch_bounds__(256) void lstm_rec(const float* __restrict__ gxf,
                                                const float* __restrict__ gxb,
                                                const __hip_bfloat162* __restrict__ wTf,
                                                const __hip_bfloat162* __restrict__ wTb,
                                                float* __restrict__ hall) {
    int blk  = blockIdx.x;        // 0..127
    int dir  = blk >> 6;
    int pos  = blk & 63;
    int j  = threadIdx.x;         // cell 0..255
    const float* gx = dir ? gxb : gxf;
    const float4* wT4 = (const float4*)(dir ? wTb : wTf);
    __shared__ float hs[256];
    hs[j] = 0.0f;
    float cc = 0.0f;
    __syncthreads();
    for (int s = 0; s < 8; ++s) {
        int t = dir ? (7 - s) : s;
        const float* g0 = gx + (size_t)(t*64 + pos)*1024;
        float ai = g0[j], af = g0[256+j], ag = g0[512+j], ao = g0[768+j];
        #pragma unroll 8
        for (int k2 = 0; k2 < 128; ++k2) {
            float4 wq = wT4[(k2 << 8) + j];
            unsigned int bi_ = __float_as_uint(wq.x);
            unsigned int bf_ = __float_as_uint(wq.y);
            unsigned int bg_ = __float_as_uint(wq.z);
            unsigned int bo_ = __float_as_uint(wq.w);
            float wix = __uint_as_float(bi_ << 16), wiy = __uint_as_float(bi_ & 0xffff0000u);
            float wfx = __uint_as_float(bf_ << 16), wfy = __uint_as_float(bf_ & 0xffff0000u);
            float wgx = __uint_as_float(bg_ << 16), wgy = __uint_as_float(bg_ & 0xffff0000u);
            float wox = __uint_as_float(bo_ << 16), woy = __uint_as_float(bo_ & 0xffff0000u);
            float2 hp = *(const float2*)&hs[2*k2];
            ai = fmaf(wix,hp.x, fmaf(wiy,hp.y, ai));
            af = fmaf(wfx,hp.x, fmaf(wfy,hp.y, af));
            ag = fmaf(wgx,hp.x, fmaf(wgy,hp.y, ag));
            ao = fmaf(wox,hp.x, fmaf(woy,hp.y, ao));
        }
        __syncthreads();
        cc = sigf(af)*cc + sigf(ai)*tanhf(ag);
        float h0 = sigf(ao)*tanhf(cc);
        hs[j] = h0;
        hall[(size_t)(t*64 + pos)*512 + dir*256 + j] = h0;
        __syncthreads();
    }
}

// ---------------------------------------------------------------- uv + p1 + p2 fused
__global__ __launch_bounds__(256) void post_lstm(const float* __restrict__ hall,
                                                 const float* __restrict__ Ws,
                                                 float* __restrict__ u, float* __restrict__ v,
                                                 const float* __restrict__ W1, const float* __restrict__ b1,
                                                 const float* __restrict__ W2, const float* __restrict__ b2,
                                                 float* __restrict__ p1, float* __restrict__ p2) {
    if (blockIdx.x < 512) {
        int bi = blockIdx.x;
        int i  = bi & 63;
        int tid = threadIdx.x;
        float pu = 0.0f, pv = 0.0f;
        for (int q = tid; q < 1536; q += 256) {
            int seg = q >> 9, kk = q & 511;
            float tv = 0.0f;
            if (seg == 0)       tv = hall[(size_t)bi*512 + kk];
            else if (seg == 1)  { if (i > 0)  tv = hall[(size_t)(bi-1)*512 + kk]; }
            else                { if (i < 63) tv = hall[(size_t)(bi+1)*512 + kk]; }
            pu = fmaf(tv, Ws[q],        pu);
            pv = fmaf(tv, Ws[1536 + q], pv);
        }
        for (int off = 32; off; off >>= 1) { pu += __shfl_xor(pu, off); pv += __shfl_xor(pv, off); }
        __shared__ float ru[4], rv[4];
        int wv = tid >> 6, lane = tid & 63;
        if (lane == 0) { ru[wv] = pu; rv[wv] = pv; }
        __syncthreads();
        if (tid == 0) { u[bi] = ru[0]+ru[1]+ru[2]+ru[3]; v[bi] = rv[0]+rv[1]+rv[2]+rv[3]; }
    } else {
        int blk = blockIdx.x - 512;        // 0..31
        int sel = blk >> 4; blk &= 15;
        gemm64_body(hall, sel ? W2 : W1, sel ? b2 : b1, sel ? p2 : p1,
                    128, 512, blk >> 1, blk & 1);
    }
}

// ---------------------------------------------------------------- Eisner + row_lse + finalize
// fp16 DP tables (halves LDS bytes AND b128 count — the measured bound),
// 8 k-terms per b128 per lane, tree-reduced max/sum chains.
// 256 blocks = 32 replicas x 8 batches (clock/busy boost; replica 0 commits).
__global__ __launch_bounds__(256) void eisner_final(const float* __restrict__ u,
                                                    const float* __restrict__ v,
                                                    const float* __restrict__ bs,
                                                    const float* __restrict__ S,
                                                    const float* __restrict__ prior,
                                                    const int* __restrict__ heads,
                                                    float* __restrict__ out) {
    int b   = blockIdx.x & 7;
    int rep = blockIdx.x >> 3;
    __shared__ __align__(16) __half Tall[3*64*TSH];
    __shared__ float su[64], sv[64], lseSb[64];
    __half* T1 = Tall;
    __half* T2 = Tall + 64*TSH;
    __half* T3 = Tall + 2*64*TSH;
    int tid = threadIdx.x;
    // init all tables to -inf (half pairs)
    unsigned int* Tw = (unsigned int*)Tall;
    for (int e = tid; e < 3*64*TSH/2; e += 256) Tw[e] = 0xFC00FC00u;
    __syncthreads();
    if (tid < 64) {
        su[tid] = u[b*64 + tid];
        sv[tid] = v[b*64 + tid];
        T1[tid*TSH + tid] = __float2half(0.0f);               // C_r diag
        T2[tid*TSH + tid] = __float2half(0.0f);               // C_l diag (row form)
        if (tid >= 1) T2[tid*TSH + tid-1] = __float2half(0.0f);  // C_l diag (col-shift)
    }
    float bsv = bs[0];
    int wvi = tid >> 6, lane = tid & 63;
    for (int r = wvi; r < 64; r += 4) {
        float x = S[(size_t)(b*64 + r)*64 + lane];
        float m = x;
        for (int off = 32; off; off >>= 1) m = fmaxf(m, __shfl_xor(m, off));
        float se = expf(x - m);
        for (int off = 32; off; off >>= 1) se += __shfl_xor(se, off);
        if (lane == 0) lseSb[r] = m + logf(se);
    }
    __syncthreads();
    int i   = tid >> 2;          // span start = quad index
    int sub = tid & 3;
    for (int w = 1; w < 64; ++w) {
        int ns = 64 - w;
        if (i < ns) {
            int j = i + w;
            const __half* t1i = &T1[i*TSH];
            const __half* t2i = &T2[i*TSH];
            const __half* t3i = &T3[i*TSH];
            const __half* t1j = &T1[j*TSH];
            const __half* t2j = &T2[j*TSH];
            const __half* t3j = &T3[j*TSH];
            int k0 = i & ~7;
            int nb = (j - k0 + 31) >> 5;   // 32-k blocks, <= 3
            float va[3][8], vr[3][8], vl[3][8];
            float m1 = -INFINITY, mr = -INFINITY, ml = -INFINITY;
            #pragma unroll
            for (int t = 0; t < 3; ++t) {
                if (t >= nb) break;
                int k = k0 + (t << 5) + (sub << 3);
                uint4 qa1 = *(const uint4*)&t1i[k];   // C_r[i][k..k+7]
                uint4 qb1 = *(const uint4*)&t2j[k];   // C_l[k+1][j]
                uint4 qa2 = *(const uint4*)&t3i[k];   // I_r[i][k]
                uint4 qb2 = *(const uint4*)&t1j[k];   // C_r[k][j]
                uint4 qa3 = *(const uint4*)&t2i[k];   // C_l[i][k]
                uint4 qb3 = *(const uint4*)&t3j[k];   // I_l[k][j]
                float A1[8], B1[8], A2[8], B2[8], A3[8], B3[8];
                cvt8(qa1, A1); cvt8(qb1, B1);
                cvt8(qa2, A2); cvt8(qb2, B2);
                cvt8(qa3, A3); cvt8(qb3, B3);
                #pragma unroll
                for (int c = 0; c < 8; ++c) {
                    int kk = k + c;
                    bool in1 = (kk >= i)   && (kk < j);
                    bool in2 = (kk >= i+1) && (kk < j);
                    va[t][c] = in1 ? A1[c] + B1[c] : -INFINITY;
                    vr[t][c] = in2 ? A2[c] + B2[c] : -INFINITY;
                    vl[t][c] = in2 ? A3[c] + B3[c] : -INFINITY;
                }
                // tree max per block
                float x1 = fmaxf(fmaxf(va[t][0],va[t][1]), fmaxf(va[t][2],va[t][3]));
                float x2 = fmaxf(fmaxf(va[t][4],va[t][5]), fmaxf(va[t][6],va[t][7]));
                m1 = fmaxf(m1, fmaxf(x1, x2));
                float y1 = fmaxf(fmaxf(vr[t][0],vr[t][1]), fmaxf(vr[t][2],vr[t][3]));
                float y2 = fmaxf(fmaxf(vr[t][4],vr[t][5]), fmaxf(vr[t][6],vr[t][7]));
                mr = fmaxf(mr, fmaxf(y1, y2));
                float z1 = fmaxf(fmaxf(vl[t][0],vl[t][1]), fmaxf(vl[t][2],vl[t][3]));
                float z2 = fmaxf(fmaxf(vl[t][4],vl[t][5]), fmaxf(vl[t][6],vl[t][7]));
                ml = fmaxf(ml, fmaxf(z1, z2));
            }
            m1 = quad_max(m1);
            mr = quad_max(mr);
            ml = quad_max(ml);
            float s1 = 0.0f, sr = 0.0f, sl = 0.0f;
            #pragma unroll
            for (int t = 0; t < 3; ++t) {
                if (t >= nb) break;
                float e0,e1,e2,e3;
                e0 = exp2f((va[t][0]-m1)*L2E) + exp2f((va[t][1]-m1)*L2E);
                e1 = exp2f((va[t][2]-m1)*L2E) + exp2f((va[t][3]-m1)*L2E);
                e2 = exp2f((va[t][4]-m1)*L2E) + exp2f((va[t][5]-m1)*L2E);
                e3 = exp2f((va[t][6]-m1)*L2E) + exp2f((va[t][7]-m1)*L2E);
                s1 += (e0+e1) + (e2+e3);
                e0 = exp2f((vr[t][0]-mr)*L2E) + exp2f((vr[t][1]-mr)*L2E);
                e1 = exp2f((vr[t][2]-mr)*L2E) + exp2f((vr[t][3]-mr)*L2E);
                e2 = exp2f((vr[t][4]-mr)*L2E) + exp2f((vr[t][5]-mr)*L2E);
                e3 = exp2f((vr[t][6]-mr)*L2E) + exp2f((vr[t][7]-mr)*L2E);
                sr += (e0+e1) + (e2+e3);
                e0 = exp2f((vl[t][0]-ml)*L2E) + exp2f((vl[t][1]-ml)*L2E);
                e1 = exp2f((vl[t][2]-ml)*L2E) + exp2f((vl[t][3]-ml)*L2E);
                e2 = exp2f((vl[t][4]-ml)*L2E) + exp2f((vl[t][5]-ml)*L2E);
                e3 = exp2f((vl[t][6]-ml)*L2E) + exp2f((vl[t][7]-ml)*L2E);
                sl += (e0+e1) + (e2+e3);
            }
            s1 = quad_sum(s1);
            sr = quad_sum(sr);
            sl = quad_sum(sl);
            float inc   = m1 + log2f(s1) * LN2;
            float partR = (mr == -INFINITY) ? -INFINITY : (mr + log2f(sr) * LN2);
            float partL = (ml == -INFINITY) ? -INFINITY : (ml + log2f(sl) * LN2);
            float Ir = inc + su[i] + sv[j] + bsv;
            float Il = inc + su[j] + sv[i] + bsv;
            float Mr = fmaxf(partR, Ir);
            float Cr = Mr + log2f(exp2f((partR - Mr) * L2E) + exp2f((Ir - Mr) * L2E)) * LN2;
            float Ml = fmaxf(partL, Il);
            float Cl = Ml + log2f(exp2f((partL - Ml) * L2E) + exp2f((Il - Ml) * L2E)) * LN2;
            if (sub == 0) {
                T3[i*TSH + j] = __float2half(Ir);               // I_r row
                T1[i*TSH + j] = __float2half(Cr);               // C_r row
                T1[j*TSH + i] = __float2half(Cr);               // C_r col
                T3[j*TSH + i] = __float2half(Il);               // I_l col
                T2[i*TSH + j] = __float2half(Cl);               // C_l row
                if (i >= 1) T2[j*TSH + i-1] = __float2half(Cl); // C_l col-shift
            }
        }
        __syncthreads();
    }
    if (rep == 0 && tid < 64) {
        int m = tid;
        float logZv = __half2float(T1[0*TSH + 63]);
        float gv = -INFINITY;
        if (m >= 1) {
            int hd = heads[b*64 + m];
            float crf = su[hd] + sv[m] + bsv;
            float rec = S[(size_t)(b*64 + hd)*64 + m] - lseSb[hd];
            gv = crf + rec + prior[(size_t)(b*64 + hd)*64 + m] * (1.0f/64.0f);
        }
        float mm = gv;
        for (int off = 32; off; off >>= 1) mm = fmaxf(mm, __shfl_xor(mm, off));
        float se = (m >= 1) ? expf(gv - mm) : 0.0f;
        for (int off = 32; off; off >>= 1) se += __shfl_xor(se, off);
        if (m == 0) {
            float red = (mm + logf(se)) - logZv;
            atomicAdd(out, -red * 0.125f);
        }
    }
}

// ---------------------------------------------------------------- launch
extern "C" void kernel_launch(void* const* d_in, const int* in_sizes, int n_in,
                              void* d_out, int out_size, void* d_ws, size_t ws_size,
                              hipStream_t stream) {
    const int*   sents = (const int*)  d_in[0];
    const float* mask  = (const float*)d_in[1];
    const float* prior = (const float*)d_in[2];
    const int*   heads = (const int*)  d_in[3];
    const float* emb   = (const float*)d_in[4];
    const float* Wih_f = (const float*)d_in[5];
    const float* Whh_f = (const float*)d_in[6];
    const float* bih_f = (const float*)d_in[7];
    const float* bhh_f = (const float*)d_in[8];
    const float* Wih_b = (const float*)d_in[9];
    const float* Whh_b = (const float*)d_in[10];
    const float* bih_b = (const float*)d_in[11];
    const float* bhh_b = (const float*)d_in[12];
    const float* W1    = (const float*)d_in[13];
    const float* b1    = (const float*)d_in[14];
    const float* W2    = (const float*)d_in[15];
    const float* b2    = (const float*)d_in[16];
    const float* Ws    = (const float*)d_in[17];
    const float* bs    = (const float*)d_in[18];
    float* out = (float*)d_out;

    char* w = (char*)d_ws;
    float* embeds = (float*)(w + 0);
    float* gxf    = (float*)(w + 524288);
    float* gxb    = (float*)(w + 2621440);
    __hip_bfloat162* wTf = (__hip_bfloat162*)(w + 4718592);
    __hip_bfloat162* wTb = (__hip_bfloat162*)(w + 5242880);
    float* biasf  = (float*)(w + 5767168);
    float* biasb  = (float*)(w + 5771264);
    float* hall   = (float*)(w + 5775360);
    float* uArr   = (float*)(w + 6823936);
    float* vArr   = (float*)(w + 6825984);
    float* p1     = (float*)(w + 6828032);
    float* p2     = (float*)(w + 7090176);
    float* S      = (float*)(w + 7352320);

    prep_all<<<1536, 256, 0, stream>>>(Whh_f, Whh_b, bih_f, bhh_f, bih_b, bhh_b,
                                       wTf, wTb, biasf, biasb,
                                       sents, mask, emb, embeds, out);
    gemm_ih<<<dim3(8,16,2), 256, 0, stream>>>(embeds, Wih_f, Wih_b, biasf, biasb, gxf, gxb);
    lstm_rec<<<128, 256, 0, stream>>>(gxf, gxb, wTf, wTb, hall);
    post_lstm<<<544, 256, 0, stream>>>(hall, Ws, uArr, vArr, W1, b1, W2, b2, p1, p2);
    gemm64<<<dim3(1,1,8), 256, 0, stream>>>(p1, p2, nullptr, S, 64, 128, 8192, 8192, 4096);
    eisner_final<<<256, 256, 0, stream>>>(uArr, vArr, bs, S, prior, heads, out);
    (void)in_sizes; (void)n_in; (void)out_size; (void)ws_size;
}

// Round 14
// 302.820 us; speedup vs baseline: 1.1041x; 1.1041x over previous
//
#include <hip/hip_runtime.h>
#include <hip/hip_bf16.h>
#include <math.h>

#define L2E 1.44269504f
#define LN2 0.69314718f
#define TSTRIDE 68

typedef __attribute__((ext_vector_type(2))) float floatx2;

__device__ __forceinline__ float sigf(float x){ return 1.0f/(1.0f+expf(-x)); }

__device__ __forceinline__ float quad_max(float x) {
    x = fmaxf(x, __int_as_float(__builtin_amdgcn_mov_dpp(__float_as_int(x), 0xB1, 0xF, 0xF, true)));
    x = fmaxf(x, __int_as_float(__builtin_amdgcn_mov_dpp(__float_as_int(x), 0x4E, 0xF, 0xF, true)));
    return x;
}
__device__ __forceinline__ float quad_sum(float x) {
    x += __int_as_float(__builtin_amdgcn_mov_dpp(__float_as_int(x), 0xB1, 0xF, 0xF, true));
    x += __int_as_float(__builtin_amdgcn_mov_dpp(__float_as_int(x), 0x4E, 0xF, 0xF, true));
    return x;
}

// ---------------------------------------------------------------- prep: embed + bias + coalesced fp8 pack
// blocks 0..511: embed mean (bias add on blocks 0/1, out-zero on block 2)
// blocks 512..639: quantize Whh -> fp8 e4m3 via LDS staging (coalesced reads).
//   qW[k4*256 + j] = uint4; dword kk (k=k4*4+kk): b0=gate_i, b1=f, b2=g, b3=o.
//   sc[j*4+g] = per-row scale.
__global__ __launch_bounds__(256) void prep_all(const float* __restrict__ Whh_f, const float* __restrict__ Whh_b,
                             const float* __restrict__ bih_f, const float* __restrict__ bhh_f,
                             const float* __restrict__ bih_b, const float* __restrict__ bhh_b,
                             uint4* __restrict__ qWf, uint4* __restrict__ qWb,
                             float* __restrict__ scf, float* __restrict__ scb,
                             float* __restrict__ biasf, float* __restrict__ biasb,
                             const int* __restrict__ sents, const float* __restrict__ mask,
                             const float* __restrict__ emb, float* __restrict__ embeds,
                             float* __restrict__ out) {
    int tid = threadIdx.x;
    if (blockIdx.x < 512) {
        int bl = blockIdx.x;
        const int*   srow = sents + bl*32;
        const float* mrow = mask  + bl*32;
        float acc = 0.0f, el = 0.0f;
        for (int w = 0; w < 32; ++w) {
            float m = mrow[w];
            el  += m;
            acc += emb[(size_t)srow[w]*256 + tid] * m;
        }
        float den = el + (el == 0.0f ? 1.0f : 0.0f);
        embeds[bl*256 + tid] = acc / den;
        if (bl == 0)      { for (int q = tid; q < 1024; q += 256) biasf[q] = bih_f[q] + bhh_f[q]; }
        else if (bl == 1) { for (int q = tid; q < 1024; q += 256) biasb[q] = bih_b[q] + bhh_b[q]; }
        else if (bl == 2 && tid == 0) out[0] = 0.0f;
    } else {
        int pb  = blockIdx.x - 512;      // 0..127
        int dir = pb >> 6;
        int cg  = pb & 63;               // cell group of 4
        const float* W = dir ? Whh_b : Whh_f;
        uint4* qW = dir ? qWb : qWf;
        float* sc = dir ? scb : scf;
        __shared__ float Wl[16][260];    // 16 rows (4 gates x 4 cells), padded
        __shared__ float sL[16];         // row scales [g*4+jj]
        // coalesced load of 16 rows
        #pragma unroll
        for (int lr = 0; lr < 16; ++lr) {
            int g = lr >> 2, jj = lr & 3;
            int rowid = g*256 + cg*4 + jj;
            Wl[lr][tid] = W[(size_t)rowid*256 + tid];
        }
        __syncthreads();
        // per-row maxabs -> scale (quads 0..15)
        if (tid < 64) {
            int lr = tid >> 2, sub = tid & 3;
            float mx = 0.0f;
            for (int m = 0; m < 64; ++m) mx = fmaxf(mx, fabsf(Wl[lr][sub*64 + m]));
            mx = quad_max(mx);
            if (sub == 0) sL[lr] = mx * (1.0f/240.0f) + 1e-30f;
        }
        __syncthreads();
        // pack: thread t -> (k4 = t>>2, jj = t&3)
        int k4 = tid >> 2, jj = tid & 3;
        float is0 = 1.0f / sL[0*4 + jj];
        float is1 = 1.0f / sL[1*4 + jj];
        float is2 = 1.0f / sL[2*4 + jj];
        float is3 = 1.0f / sL[3*4 + jj];
        uint4 q;
        unsigned int* qq = (unsigned int*)&q;
        #pragma unroll
        for (int kk = 0; kk < 4; ++kk) {
            int k = k4*4 + kk;
            int d = 0;
            d = __builtin_amdgcn_cvt_pk_fp8_f32(Wl[0*4+jj][k]*is0, Wl[1*4+jj][k]*is1, d, false);
            d = __builtin_amdgcn_cvt_pk_fp8_f32(Wl[2*4+jj][k]*is2, Wl[3*4+jj][k]*is3, d, true);
            qq[kk] = (unsigned int)d;
        }
        qW[k4*256 + cg*4 + jj] = q;
        if (tid < 16) {
            int g = tid >> 2, j2 = tid & 3;
            sc[(cg*4 + j2)*4 + g] = sL[g*4 + j2];
        }
    }
}

// ---------------------------------------------------------------- 64x64 GEMM body, 4x4 micro-tile
__device__ __forceinline__ void gemm64_body(const float* __restrict__ A,
                                            const float* __restrict__ Bm,
                                            const float* __restrict__ bias,
                                            float* __restrict__ C,
                                            int N, int K, int bx, int by) {
    __shared__ __align__(16) float As[32][68];
    __shared__ __align__(16) float Bs[32][68];
    int tid = threadIdx.x;
    int tx = tid & 15, ty = tid >> 4;
    int row0 = bx * 64, col0 = by * 64;
    float acc[4][4];
    #pragma unroll
    for (int r = 0; r < 4; ++r)
        #pragma unroll
        for (int c = 0; c < 4; ++c) acc[r][c] = 0.0f;
    int lr = tid >> 2;
    int lc = (tid & 3) * 8;
    for (int k0 = 0; k0 < K; k0 += 32) {
        float4 a0 = *(const float4*)(A  + (size_t)(row0+lr)*K + k0 + lc);
        float4 a1 = *(const float4*)(A  + (size_t)(row0+lr)*K + k0 + lc + 4);
        float4 b0 = *(const float4*)(Bm + (size_t)(col0+lr)*K + k0 + lc);
        float4 b1 = *(const float4*)(Bm + (size_t)(col0+lr)*K + k0 + lc + 4);
        As[lc  ][lr] = a0.x; As[lc+1][lr] = a0.y; As[lc+2][lr] = a0.z; As[lc+3][lr] = a0.w;
        As[lc+4][lr] = a1.x; As[lc+5][lr] = a1.y; As[lc+6][lr] = a1.z; As[lc+7][lr] = a1.w;
        Bs[lc  ][lr] = b0.x; Bs[lc+1][lr] = b0.y; Bs[lc+2][lr] = b0.z; Bs[lc+3][lr] = b0.w;
        Bs[lc+4][lr] = b1.x; Bs[lc+5][lr] = b1.y; Bs[lc+6][lr] = b1.z; Bs[lc+7][lr] = b1.w;
        __syncthreads();
        #pragma unroll
        for (int kc = 0; kc < 32; ++kc) {
            float4 xa = *(const float4*)&As[kc][ty*4];
            float4 xb = *(const float4*)&Bs[kc][tx*4];
            acc[0][0] = fmaf(xa.x, xb.x, acc[0][0]);
            acc[0][1] = fmaf(xa.x, xb.y, acc[0][1]);
            acc[0][2] = fmaf(xa.x, xb.z, acc[0][2]);
            acc[0][3] = fmaf(xa.x, xb.w, acc[0][3]);
            acc[1][0] = fmaf(xa.y, xb.x, acc[1][0]);
            acc[1][1] = fmaf(xa.y, xb.y, acc[1][1]);
            acc[1][2] = fmaf(xa.y, xb.z, acc[1][2]);
            acc[1][3] = fmaf(xa.y, xb.w, acc[1][3]);
            acc[2][0] = fmaf(xa.z, xb.x, acc[2][0]);
            acc[2][1] = fmaf(xa.z, xb.y, acc[2][1]);
            acc[2][2] = fmaf(xa.z, xb.z, acc[2][2]);
            acc[2][3] = fmaf(xa.z, xb.w, acc[2][3]);
            acc[3][0] = fmaf(xa.w, xb.x, acc[3][0]);
            acc[3][1] = fmaf(xa.w, xb.y, acc[3][1]);
            acc[3][2] = fmaf(xa.w, xb.z, acc[3][2]);
            acc[3][3] = fmaf(xa.w, xb.w, acc[3][3]);
        }
        __syncthreads();
    }
    float4 bv = bias ? *(const float4*)&bias[col0 + tx*4] : make_float4(0.f,0.f,0.f,0.f);
    #pragma unroll
    for (int r = 0; r < 4; ++r) {
        float4 o;
        o.x = acc[r][0] + bv.x; o.y = acc[r][1] + bv.y;
        o.z = acc[r][2] + bv.z; o.w = acc[r][3] + bv.w;
        *(float4*)(C + (size_t)(row0 + ty*4 + r)*N + col0 + tx*4) = o;
    }
}

__global__ __launch_bounds__(256) void gemm_ih(const float* __restrict__ embeds,
                                               const float* __restrict__ Wf, const float* __restrict__ Wb,
                                               const float* __restrict__ biasf, const float* __restrict__ biasb,
                                               float* __restrict__ gxf, float* __restrict__ gxb) {
    int dir = blockIdx.z;
    gemm64_body(embeds, dir ? Wb : Wf, dir ? biasb : biasf, dir ? gxb : gxf,
                1024, 256, blockIdx.x, blockIdx.y);
}

__global__ __launch_bounds__(256) void gemm64(const float* __restrict__ A,
                                              const float* __restrict__ Bm,
                                              const float* __restrict__ bias,
                                              float* __restrict__ C,
                                              int N, int K, int sA, int sB, int sC) {
    gemm64_body(A + (size_t)blockIdx.z * sA, Bm + (size_t)blockIdx.z * sB, bias,
                C + (size_t)blockIdx.z * sC, N, K, blockIdx.x, blockIdx.y);
}

// ---------------------------------------------------------------- LSTM recurrence (fp8 weights, R11 body)
// 128 blocks = (dir, position). Per k4: one dwordx4 = 4 k x 4 gates fp8,
// HW pk decode; per-row scale applied after accumulation. Halves the
// per-CU L1 weight stream vs bf16 (the measured bound).
__global__ __launch_bounds__(256) void lstm_rec(const float* __restrict__ gxf,
                                                const float* __restrict__ gxb,
                                                const uint4* __restrict__ qWf,
                                                const uint4* __restrict__ qWb,
                                                const float* __restrict__ scf,
                                                const float* __restrict__ scb,
                                                float* __restrict__ hall) {
    int blk  = blockIdx.x;        // 0..127
    int dir  = blk >> 6;
    int pos  = blk & 63;
    int j  = threadIdx.x;         // cell 0..255
    const float* gx = dir ? gxb : gxf;
    const uint4* qW = dir ? qWb : qWf;
    float4 sc = ((const float4*)(dir ? scb : scf))[j];
    __shared__ __align__(16) float hs[256];
    hs[j] = 0.0f;
    float cellc = 0.0f;
    __syncthreads();
    for (int s = 0; s < 8; ++s) {
        int t = dir ? (7 - s) : s;
        const float* g0 = gx + (size_t)(t*64 + pos)*1024;
        float ai = g0[j], af = g0[256+j], ag = g0[512+j], ao = g0[768+j];
        float qi = 0.0f, qf = 0.0f, qg = 0.0f, qo = 0.0f;
        #pragma unroll 8
        for (int k4 = 0; k4 < 64; ++k4) {
            uint4 wq = qW[(k4 << 8) + j];
            float4 hp = *(const float4*)&hs[k4*4];
            floatx2 pa, pb;
            pa = __builtin_amdgcn_cvt_pk_f32_fp8(wq.x, false);
            pb = __builtin_amdgcn_cvt_pk_f32_fp8(wq.x, true);
            qi = fmaf(pa.x, hp.x, qi); qf = fmaf(pa.y, hp.x, qf);
            qg = fmaf(pb.x, hp.x, qg); qo = fmaf(pb.y, hp.x, qo);
            pa = __builtin_amdgcn_cvt_pk_f32_fp8(wq.y, false);
            pb = __builtin_amdgcn_cvt_pk_f32_fp8(wq.y, true);
            qi = fmaf(pa.x, hp.y, qi); qf = fmaf(pa.y, hp.y, qf);
            qg = fmaf(pb.x, hp.y, qg); qo = fmaf(pb.y, hp.y, qo);
            pa = __builtin_amdgcn_cvt_pk_f32_fp8(wq.z, false);
            pb = __builtin_amdgcn_cvt_pk_f32_fp8(wq.z, true);
            qi = fmaf(pa.x, hp.z, qi); qf = fmaf(pa.y, hp.z, qf);
            qg = fmaf(pb.x, hp.z, qg); qo = fmaf(pb.y, hp.z, qo);
            pa = __builtin_amdgcn_cvt_pk_f32_fp8(wq.w, false);
            pb = __builtin_amdgcn_cvt_pk_f32_fp8(wq.w, true);
            qi = fmaf(pa.x, hp.w, qi); qf = fmaf(pa.y, hp.w, qf);
            qg = fmaf(pb.x, hp.w, qg); qo = fmaf(pb.y, hp.w, qo);
        }
        ai = fmaf(sc.x, qi, ai);
        af = fmaf(sc.y, qf, af);
        ag = fmaf(sc.z, qg, ag);
        ao = fmaf(sc.w, qo, ao);
        __syncthreads();
        cellc = sigf(af)*cellc + sigf(ai)*tanhf(ag);
        float h0 = sigf(ao)*tanhf(cellc);
        hs[j] = h0;
        hall[(size_t)(t*64 + pos)*512 + dir*256 + j] = h0;
        __syncthreads();
    }
}

// ---------------------------------------------------------------- uv + p1 + p2 fused
__global__ __launch_bounds__(256) void post_lstm(const float* __restrict__ hall,
                                                 const float* __restrict__ Ws,
                                                 float* __restrict__ u, float* __restrict__ v,
                                                 const float* __restrict__ W1, const float* __restrict__ b1,
                                                 const float* __restrict__ W2, const float* __restrict__ b2,
                                                 float* __restrict__ p1, float* __restrict__ p2) {
    if (blockIdx.x < 512) {
        int bi = blockIdx.x;
        int i  = bi & 63;
        int tid = threadIdx.x;
        float pu = 0.0f, pv = 0.0f;
        for (int q = tid; q < 1536; q += 256) {
            int seg = q >> 9, kk = q & 511;
            float tv = 0.0f;
            if (seg == 0)       tv = hall[(size_t)bi*512 + kk];
            else if (seg == 1)  { if (i > 0)  tv = hall[(size_t)(bi-1)*512 + kk]; }
            else                { if (i < 63) tv = hall[(size_t)(bi+1)*512 + kk]; }
            pu = fmaf(tv, Ws[q],        pu);
            pv = fmaf(tv, Ws[1536 + q], pv);
        }
        for (int off = 32; off; off >>= 1) { pu += __shfl_xor(pu, off); pv += __shfl_xor(pv, off); }
        __shared__ float ru[4], rv[4];
        int wv = tid >> 6, lane = tid & 63;
        if (lane == 0) { ru[wv] = pu; rv[wv] = pv; }
        __syncthreads();
        if (tid == 0) { u[bi] = ru[0]+ru[1]+ru[2]+ru[3]; v[bi] = rv[0]+rv[1]+rv[2]+rv[3]; }
    } else {
        int blk = blockIdx.x - 512;        // 0..31
        int sel = blk >> 4; blk &= 15;
        gemm64_body(hall, sel ? W2 : W1, sel ? b2 : b1, sel ? p2 : p1,
                    128, 512, blk >> 1, blk & 1);
    }
}

// ---------------------------------------------------------------- Eisner + row_lse + finalize (R10 fp32 version)
// 256 blocks = 32 replicas x 8 batches (busy/clock boost; replica 0 commits).
__global__ __launch_bounds__(256) void eisner_final(const float* __restrict__ u,
                                                    const float* __restrict__ v,
                                                    const float* __restrict__ bs,
                                                    const float* __restrict__ S,
                                                    const float* __restrict__ prior,
                                                    const int* __restrict__ heads,
                                                    float* __restrict__ out) {
    int b   = blockIdx.x & 7;
    int rep = blockIdx.x >> 3;
    __shared__ __align__(16) float Tall[3*64*TSTRIDE + 64];
    __shared__ float su[64], sv[64], lseSb[64];
    float* T1 = &Tall[0];
    float* T2 = &Tall[64*TSTRIDE];
    float* T3 = &Tall[2*64*TSTRIDE];
    int tid = threadIdx.x;
    if (tid < 64) {
        su[tid] = u[b*64 + tid];
        sv[tid] = v[b*64 + tid];
        T1[tid*TSTRIDE + tid] = 0.0f;
        T2[tid*TSTRIDE + tid] = 0.0f;
        if (tid >= 1) T2[tid*TSTRIDE + tid-1] = 0.0f;
    }
    float bsv = bs[0];
    int wvi = tid >> 6, lane = tid & 63;
    for (int r = wvi; r < 64; r += 4) {
        float x = S[(size_t)(b*64 + r)*64 + lane];
        float m = x;
        for (int off = 32; off; off >>= 1) m = fmaxf(m, __shfl_xor(m, off));
        float se = expf(x - m);
        for (int off = 32; off; off >>= 1) se += __shfl_xor(se, off);
        if (lane == 0) lseSb[r] = m + logf(se);
    }
    __syncthreads();
    int i   = tid >> 2;
    int sub = tid & 3;
    for (int w = 1; w < 64; ++w) {
        int ns = 64 - w;
        if (i < ns) {
            int j = i + w;
            const float* t1i = &T1[i*TSTRIDE];
            const float* t2i = &T2[i*TSTRIDE];
            const float* t3i = &T3[i*TSTRIDE];
            const float* t1j = &T1[j*TSTRIDE];
            const float* t2j = &T2[j*TSTRIDE];
            const float* t3j = &T3[j*TSTRIDE];
            int k0 = i & ~3;
            int nb = (j - k0 + 15) >> 4;
            float va[4][4], vr[4][4], vl[4][4];
            float m1 = -INFINITY, mr = -INFINITY, ml = -INFINITY;
            #pragma unroll
            for (int t = 0; t < 4; ++t) {
                if (t >= nb) break;
                int k = k0 + (t << 4) + (sub << 2);
                float4 a1 = *(const float4*)&t1i[k];
                float4 b1 = *(const float4*)&t2j[k];
                float4 a2 = *(const float4*)&t3i[k];
                float4 b2v = *(const float4*)&t1j[k];
                float4 a3 = *(const float4*)&t2i[k];
                float4 b3 = *(const float4*)&t3j[k];
                #pragma unroll
                for (int c = 0; c < 4; ++c) {
                    int kk = k + c;
                    bool in1 = (kk >= i   && kk < j);
                    bool in2 = (kk >= i+1 && kk < j);
                    float x1 = ((const float*)&a1)[c] + ((const float*)&b1)[c];
                    float x2 = ((const float*)&a2)[c] + ((const float*)&b2v)[c];
                    float x3 = ((const float*)&a3)[c] + ((const float*)&b3)[c];
                    va[t][c] = in1 ? x1 : -INFINITY;
                    vr[t][c] = in2 ? x2 : -INFINITY;
                    vl[t][c] = in2 ? x3 : -INFINITY;
                    m1 = fmaxf(m1, va[t][c]);
                    mr = fmaxf(mr, vr[t][c]);
                    ml = fmaxf(ml, vl[t][c]);
                }
            }
            m1 = quad_max(m1);
            mr = quad_max(mr);
            ml = quad_max(ml);
            float s1 = 0.0f, sr = 0.0f, sl = 0.0f;
            #pragma unroll
            for (int t = 0; t < 4; ++t) {
                if (t >= nb) break;
                #pragma unroll
                for (int c = 0; c < 4; ++c) {
                    s1 += exp2f((va[t][c] - m1) * L2E);
                    sr += exp2f((vr[t][c] - mr) * L2E);
                    sl += exp2f((vl[t][c] - ml) * L2E);
                }
            }
            s1 = quad_sum(s1);
            sr = quad_sum(sr);
            sl = quad_sum(sl);
            float inc   = m1 + log2f(s1) * LN2;
            float partR = (mr == -INFINITY) ? -INFINITY : (mr + log2f(sr) * LN2);
            float partL = (ml == -INFINITY) ? -INFINITY : (ml + log2f(sl) * LN2);
            float Ir = inc + su[i] + sv[j] + bsv;
            float Il = inc + su[j] + sv[i] + bsv;
            float Mr = fmaxf(partR, Ir);
            float Cr = Mr + log2f(exp2f((partR - Mr) * L2E) + exp2f((Ir - Mr) * L2E)) * LN2;
            float Ml = fmaxf(partL, Il);
            float Cl = Ml + log2f(exp2f((partL - Ml) * L2E) + exp2f((Il - Ml) * L2E)) * LN2;
            if (sub == 0) {
                T3[i*TSTRIDE + j] = Ir;
                T1[i*TSTRIDE + j] = Cr;
                T1[j*TSTRIDE + i] = Cr;
                T3[j*TSTRIDE + i] = Il;
                T2[i*TSTRIDE + j] = Cl;
                if (i >= 1) T2[j*TSTRIDE + i-1] = Cl;
            }
        }
        __syncthreads();
    }
    if (rep == 0 && tid < 64) {
        int m = tid;
        float logZv = T1[0*TSTRIDE + 63];
        float gv = -INFINITY;
        if (m >= 1) {
            int hd = heads[b*64 + m];
            float crf = su[hd] + sv[m] + bsv;
            float rec = S[(size_t)(b*64 + hd)*64 + m] - lseSb[hd];
            gv = crf + rec + prior[(size_t)(b*64 + hd)*64 + m] * (1.0f/64.0f);
        }
        float mm = gv;
        for (int off = 32; off; off >>= 1) mm = fmaxf(mm, __shfl_xor(mm, off));
        float se = (m >= 1) ? expf(gv - mm) : 0.0f;
        for (int off = 32; off; off >>= 1) se += __shfl_xor(se, off);
        if (m == 0) {
            float red = (mm + logf(se)) - logZv;
            atomicAdd(out, -red * 0.125f);
        }
    }
}

// ---------------------------------------------------------------- launch
extern "C" void kernel_launch(void* const* d_in, const int* in_sizes, int n_in,
                              void* d_out, int out_size, void* d_ws, size_t ws_size,
                              hipStream_t stream) {
    const int*   sents = (const int*)  d_in[0];
    const float* mask  = (const float*)d_in[1];
    const float* prior = (const float*)d_in[2];
    const int*   heads = (const int*)  d_in[3];
    const float* emb   = (const float*)d_in[4];
    const float* Wih_f = (const float*)d_in[5];
    const float* Whh_f = (const float*)d_in[6];
    const float* bih_f = (const float*)d_in[7];
    const float* bhh_f = (const float*)d_in[8];
    const float* Wih_b = (const float*)d_in[9];
    const float* Whh_b = (const float*)d_in[10];
    const float* bih_b = (const float*)d_in[11];
    const float* bhh_b = (const float*)d_in[12];
    const float* W1    = (const float*)d_in[13];
    const float* b1    = (const float*)d_in[14];
    const float* W2    = (const float*)d_in[15];
    const float* b2    = (const float*)d_in[16];
    const float* Ws    = (const float*)d_in[17];
    const float* bs    = (const float*)d_in[18];
    float* out = (float*)d_out;

    char* w = (char*)d_ws;
    float* embeds = (float*)(w + 0);                 // 512 KB
    float* gxf    = (float*)(w + 524288);            // 2 MB
    float* gxb    = (float*)(w + 2621440);           // 2 MB
    uint4* qWf    = (uint4*)(w + 4718592);           // 256 KB
    uint4* qWb    = (uint4*)(w + 4980736);           // 256 KB
    float* scf    = (float*)(w + 5242880);           // 4 KB
    float* scb    = (float*)(w + 5246976);           // 4 KB
    float* biasf  = (float*)(w + 5767168);           // 4 KB
    float* biasb  = (float*)(w + 5771264);           // 4 KB
    float* hall   = (float*)(w + 5775360);           // 1 MB
    float* uArr   = (float*)(w + 6823936);
    float* vArr   = (float*)(w + 6825984);
    float* p1     = (float*)(w + 6828032);
    float* p2     = (float*)(w + 7090176);
    float* S      = (float*)(w + 7352320);

    prep_all<<<640, 256, 0, stream>>>(Whh_f, Whh_b, bih_f, bhh_f, bih_b, bhh_b,
                                      qWf, qWb, scf, scb, biasf, biasb,
                                      sents, mask, emb, embeds, out);
    gemm_ih<<<dim3(8,16,2), 256, 0, stream>>>(embeds, Wih_f, Wih_b, biasf, biasb, gxf, gxb);
    lstm_rec<<<128, 256, 0, stream>>>(gxf, gxb, qWf, qWb, scf, scb, hall);
    post_lstm<<<544, 256, 0, stream>>>(hall, Ws, uArr, vArr, W1, b1, W2, b2, p1, p2);
    gemm64<<<dim3(1,1,8), 256, 0, stream>>>(p1, p2, nullptr, S, 64, 128, 8192, 8192, 4096);
    eisner_final<<<256, 256, 0, stream>>>(uArr, vArr, bs, S, prior, heads, out);
    (void)in_sizes; (void)n_in; (void)out_size; (void)ws_size;
}